// Round 15
// baseline (175.689 us; speedup 1.0000x reference)
//
#include <hip/hip_runtime.h>
#include <hip/hip_bf16.h>
#include <cstdint>
#include <cstddef>

#define HEADS 12
#define HD    64
#define NB    4
#define SEQ   2048
#define DIM   768
#define NQKV  2304

// Q pre-scale: (1/sqrt(HEADS)) * log2(e)  -> scores arrive in exp2 domain
static constexpr float QSCALE = 0.2886751345948129f * 1.4426950408889634f;

typedef __attribute__((ext_vector_type(8))) short short8;
typedef __attribute__((ext_vector_type(4))) short short4v;
typedef __attribute__((ext_vector_type(4))) float f32x4;

__device__ inline unsigned short f2bf(float x) {          // RNE, for cold paths
    union { float f; uint32_t u; } v; v.f = x;
    return (unsigned short)((v.u + 0x7fffu + ((v.u >> 16) & 1u)) >> 16);
}

__device__ inline unsigned short f2bf_fast(float x) {     // compiler hw-convert
    __hip_bfloat16 h = __float2bfloat16(x);
    unsigned short u;
    __builtin_memcpy(&u, &h, 2);
    return u;
}

__device__ inline void gld16(const void* g, void* l) {
    __builtin_amdgcn_global_load_lds(
        (const __attribute__((address_space(1))) unsigned int*)g,
        (__attribute__((address_space(3))) unsigned int*)l, 16, 0, 0);
}

// ---------------------------------------------------------------------------
// Fused prep kernel: x->bf16 convert + both weight transpose-converts.
// ---------------------------------------------------------------------------
__device__ inline void transpose_tile(
    const float* __restrict__ w, unsigned short* __restrict__ wT,
    int ncols, int nrows, int bx, int by, float (*tile)[65])
{
    const int k0 = by * 64;
    const int n0 = bx * 64;
    const int tr = threadIdx.x >> 4;
    const int tc4 = (threadIdx.x & 15) * 4;
    #pragma unroll
    for (int it = 0; it < 4; ++it) {
        const int kk = tr + it * 16;
        *reinterpret_cast<float4*>(&tile[kk][tc4]) =
            *reinterpret_cast<const float4*>(w + (size_t)(k0 + kk) * ncols + n0 + tc4);
    }
    __syncthreads();
    #pragma unroll
    for (int it = 0; it < 4; ++it) {
        const int nn = tr + it * 16;
        short4v o;
        #pragma unroll
        for (int r = 0; r < 4; ++r) o[r] = (short)f2bf(tile[tc4 + r][nn]);
        *reinterpret_cast<short4v*>(wT + (size_t)(n0 + nn) * nrows + k0 + tc4) = o;
    }
}

__global__ __launch_bounds__(256) void prep_kernel(
    const float* __restrict__ x, unsigned short* __restrict__ xb,
    const float* __restrict__ wq, unsigned short* __restrict__ wqT,
    const float* __restrict__ wo, unsigned short* __restrict__ woT)
{
    __shared__ float tile[64][65];
    const int bid = blockIdx.x;
    if (bid < 3072) {
        const size_t i = ((size_t)bid * 256 + threadIdx.x) * 8;
        const float4 a = *reinterpret_cast<const float4*>(x + i);
        const float4 b = *reinterpret_cast<const float4*>(x + i + 4);
        short8 o;
        o[0] = (short)f2bf(a.x); o[1] = (short)f2bf(a.y);
        o[2] = (short)f2bf(a.z); o[3] = (short)f2bf(a.w);
        o[4] = (short)f2bf(b.x); o[5] = (short)f2bf(b.y);
        o[6] = (short)f2bf(b.z); o[7] = (short)f2bf(b.w);
        *reinterpret_cast<short8*>(xb + i) = o;
    } else if (bid < 3072 + 432) {
        const int r = bid - 3072;
        transpose_tile(wq, wqT, NQKV, DIM, r % 36, r / 36, tile);
    } else {
        const int r = bid - 3504;
        transpose_tile(wo, woT, DIM, DIM, r % 12, r / 12, tile);
    }
}

// ---------------------------------------------------------------------------
// Kernel 1: QKV GEMM, bf16 MFMA, T3-minimal 2-phase (R10 form, proven).
// ---------------------------------------------------------------------------
__global__ __launch_bounds__(512) void qkv_gemm_bf16(
    const unsigned short* __restrict__ A,   // [8192][768]
    const unsigned short* __restrict__ BT,  // [2304][768]
    const float* __restrict__ bias,
    unsigned short* __restrict__ qb, unsigned short* __restrict__ kb,
    unsigned short* __restrict__ vt)
{
    __shared__ __align__(16) unsigned short As[2][128][64];
    __shared__ __align__(16) unsigned short Bs[2][128][64];

    const int tid = threadIdx.x;
    const int wave = tid >> 6;        // 0..7
    const int lane = tid & 63;
    const int col = lane & 15;
    const int g = lane >> 4;
    const int m0 = blockIdx.y * 128;
    const int n0 = blockIdx.x * 128;
    const int wr = wave >> 2;         // 0..1  row half (64 rows)
    const int wc = wave & 3;          // 0..3  col quarter (32 cols)

    f32x4 acc[4][2] = {};

    auto STAGE = [&](int kt, int bsel) {
        #pragma unroll
        for (int it = 0; it < 2; ++it) {
            const int slot = tid + it * 512;
            const int row = slot >> 3;
            const int cg = (slot & 7) ^ (row & 7);
            gld16(A + (size_t)(m0 + row) * DIM + kt + cg * 8,
                  &As[bsel][0][0] + (size_t)slot * 8);
            gld16(BT + (size_t)(n0 + row) * DIM + kt + cg * 8,
                  &Bs[bsel][0][0] + (size_t)slot * 8);
        }
    };

    const int NKT = DIM / 64;   // 12
    STAGE(0, 0);
    asm volatile("s_waitcnt vmcnt(0)" ::: "memory");
    __builtin_amdgcn_s_barrier();

    for (int t = 0; t < NKT; ++t) {
        const int cur = t & 1;
        if (t + 1 < NKT) STAGE((t + 1) * 64, cur ^ 1);  // overlap with compute

        #pragma unroll
        for (int ks = 0; ks < 2; ++ks) {
            short8 af[4], bf[2];
            #pragma unroll
            for (int i = 0; i < 4; ++i) {
                const int ra = wr * 64 + i * 16 + col;
                af[i] = *reinterpret_cast<const short8*>(
                    &As[cur][ra][(((ks * 4 + g) ^ (ra & 7)) << 3)]);
            }
            #pragma unroll
            for (int j = 0; j < 2; ++j) {
                const int rb = wc * 32 + j * 16 + col;
                bf[j] = *reinterpret_cast<const short8*>(
                    &Bs[cur][rb][(((ks * 4 + g) ^ (rb & 7)) << 3)]);
            }
            #pragma unroll
            for (int i = 0; i < 4; ++i)
                #pragma unroll
                for (int j = 0; j < 2; ++j)
                    acc[i][j] = __builtin_amdgcn_mfma_f32_16x16x32_bf16(
                        af[i], bf[j], acc[i][j], 0, 0, 0);
        }

        if (t + 1 < NKT) {
            asm volatile("s_waitcnt vmcnt(0)" ::: "memory");  // t+1 tile landed
            __builtin_amdgcn_s_barrier();  // + all waves done reading buf[cur]
        }
    }

    // Epilogue: bias + bf16 scatter. which is block-uniform (768 % 128 == 0).
    const int which = n0 / DIM;
    #pragma unroll
    for (int j = 0; j < 2; ++j) {
        const int n = n0 + wc * 32 + j * 16 + col;
        const int rem = n - which * DIM;
        const int h = rem >> 6, dh = rem & 63;
        const float bj = bias[n];
        #pragma unroll
        for (int i = 0; i < 4; ++i) {
            const int mbase = m0 + wr * 64 + i * 16 + g * 4;
            const int b_ = mbase >> 11;
            const int s_ = mbase & 2047;
            const size_t bh = (size_t)(b_ * HEADS + h);
            if (which == 2) {
                short4v pk;
                #pragma unroll
                for (int r = 0; r < 4; ++r)
                    pk[r] = (short)f2bf(acc[i][j][r] + bj);
                *reinterpret_cast<short4v*>(vt + (bh * HD + dh) * SEQ + s_) = pk;
            } else {
                unsigned short* dst = (which == 0) ? qb : kb;
                const float sc = (which == 0) ? QSCALE : 1.0f;
                #pragma unroll
                for (int r = 0; r < 4; ++r)
                    dst[(bh * SEQ + s_ + r) * HD + dh] =
                        f2bf((acc[i][j][r] + bj) * sc);
            }
        }
    }
}

// ---------------------------------------------------------------------------
// Kernel 2: flash attention — q-register-blocked: 4 waves x 32 q-rows
// (2 strips of 16). Same K/V fragment reads now feed 2x the MFMAs ->
// LDS bytes per FLOP ~0.64x (the measured plateau was LDS-BW-bound).
// R13 skeleton kept: dbuf K/V, counted vmcnt(4), 2 barriers/tile, XCD
// swizzle, setprio, ones-MFMA row-sum. 256 threads, 48 KB LDS.
// ---------------------------------------------------------------------------
__global__ __launch_bounds__(256) void attn_kernel(
    const unsigned short* __restrict__ qb, const unsigned short* __restrict__ kbuf,
    const unsigned short* __restrict__ vt, unsigned short* __restrict__ ctxb)
{
    __shared__ __align__(16) unsigned short Ks[2][64][64];    // [buf][key][hd]
    __shared__ __align__(16) unsigned short Vs[2][64][64];    // [buf][hd][key]
    __shared__ __align__(16) unsigned short Ps[4][2][16][64]; // [wave][strip][q][key]

    const int tid = threadIdx.x;
    const int wave = tid >> 6;      // 0..3
    const int lane = tid & 63;
    const int col = lane & 15;
    const int g   = lane >> 4;

    // XCD swizzle: grid = 768 blocks = 8 XCDs x 96; XCD i gets bh in [i*6,i*6+6)
    const int bid = blockIdx.x;
    const int vbid = (bid & 7) * 96 + (bid >> 3);
    const int bh = vbid >> 4;          // 0..47
    const int q0 = (vbid & 15) * 128;  // q-tile

    const size_t hb = (size_t)bh * SEQ * HD;

    // Q fragments for both 16-row strips (pre-scaled bf16)
    short8 qf[2][2];
    #pragma unroll
    for (int qs = 0; qs < 2; ++qs) {
        const unsigned short* src =
            qb + hb + (size_t)(q0 + wave * 32 + qs * 16 + col) * HD + g * 8;
        qf[qs][0] = *reinterpret_cast<const short8*>(src);
        qf[qs][1] = *reinterpret_cast<const short8*>(src + 32);
    }

    const short ONE = (short)0x3F80;
    const short8 ONES = {ONE, ONE, ONE, ONE, ONE, ONE, ONE, ONE};

    f32x4 acc4[2][4] = {};
    f32x4 acc5[2] = {};          // running row-sum of P per strip

    const unsigned short* Kg = kbuf + hb;
    const unsigned short* Vg = vt + hb;

    // staging: 256 threads, 2 K-chunks + 2 V-chunks each (64 rows x 8 chunks)
    const int srow = tid >> 3;       // 0..31
    const int scl  = tid & 7;

    auto STAGE = [&](int jt, int bsel) {
        const int kb0 = jt * 64;
        #pragma unroll
        for (int it = 0; it < 2; ++it) {
            const int row = srow + it * 32;
            const int cg = scl ^ (row & 7);
            gld16(Kg + (size_t)(kb0 + row) * HD + cg * 8,
                  &Ks[bsel][0][0] + (size_t)(it * 256 + tid) * 8);
            gld16(Vg + (size_t)row * SEQ + kb0 + cg * 8,
                  &Vs[bsel][0][0] + (size_t)(it * 256 + tid) * 8);
        }
    };

    const int NT = SEQ / 64;
    STAGE(0, 0);

    for (int jt = 0; jt < NT; ++jt) {
        const int cur = jt & 1;
        if (jt + 1 < NT) {
            STAGE(jt + 1, cur ^ 1);                          // prefetch next
            asm volatile("s_waitcnt vmcnt(4)" ::: "memory"); // tile jt landed
        } else {
            asm volatile("s_waitcnt vmcnt(0)" ::: "memory");
        }
        __builtin_amdgcn_s_barrier();   // all waves' tile-jt loads visible

        // S^T = K · Q^T  — K fragments shared across both q-strips
        f32x4 st[2][4] = {};
        __builtin_amdgcn_s_setprio(1);
        #pragma unroll
        for (int m = 0; m < 4; ++m) {
            const int row = m * 16 + col;
            const short8 kf0 = *reinterpret_cast<const short8*>(
                &Ks[cur][row][((g ^ (row & 7)) << 3)]);
            const short8 kf1 = *reinterpret_cast<const short8*>(
                &Ks[cur][row][(((g + 4) ^ (row & 7)) << 3)]);
            #pragma unroll
            for (int qs = 0; qs < 2; ++qs) {
                st[qs][m] = __builtin_amdgcn_mfma_f32_16x16x32_bf16(
                    kf0, qf[qs][0], st[qs][m], 0, 0, 0);
                st[qs][m] = __builtin_amdgcn_mfma_f32_16x16x32_bf16(
                    kf1, qf[qs][1], st[qs][m], 0, 0, 0);
            }
        }
        __builtin_amdgcn_s_setprio(0);

        // p = exp2(s); stage P as bf16 (wave-private LDS), both strips
        #pragma unroll
        for (int qs = 0; qs < 2; ++qs) {
            #pragma unroll
            for (int m = 0; m < 4; ++m) {
                float p[4];
                p[0] = __builtin_amdgcn_exp2f(st[qs][m][0]);
                p[1] = __builtin_amdgcn_exp2f(st[qs][m][1]);
                p[2] = __builtin_amdgcn_exp2f(st[qs][m][2]);
                p[3] = __builtin_amdgcn_exp2f(st[qs][m][3]);
                short4v pk;
                #pragma unroll
                for (int r = 0; r < 4; ++r) pk[r] = (short)f2bf_fast(p[r]);
                const int scw = (2 * m + (g >> 1)) ^ (col & 7);
                *reinterpret_cast<short4v*>(
                    &Ps[wave][qs][col][(scw << 3) + ((g & 1) << 2)]) = pk;
            }
        }

        short8 pf[2][2];
        #pragma unroll
        for (int qs = 0; qs < 2; ++qs) {
            pf[qs][0] = *reinterpret_cast<const short8*>(
                &Ps[wave][qs][col][((g ^ (col & 7)) << 3)]);
            pf[qs][1] = *reinterpret_cast<const short8*>(
                &Ps[wave][qs][col][(((g + 4) ^ (col & 7)) << 3)]);
        }

        // acc += P @ V — V fragments shared across both q-strips;
        // row-sum via ones-MFMA on the matrix pipe
        __builtin_amdgcn_s_setprio(1);
        #pragma unroll
        for (int nb = 0; nb < 4; ++nb) {
            const int row = nb * 16 + col;
            const short8 vf0 = *reinterpret_cast<const short8*>(
                &Vs[cur][row][((g ^ (row & 7)) << 3)]);
            const short8 vf1 = *reinterpret_cast<const short8*>(
                &Vs[cur][row][(((g + 4) ^ (row & 7)) << 3)]);
            #pragma unroll
            for (int qs = 0; qs < 2; ++qs) {
                acc4[qs][nb] = __builtin_amdgcn_mfma_f32_16x16x32_bf16(
                    pf[qs][0], vf0, acc4[qs][nb], 0, 0, 0);
                acc4[qs][nb] = __builtin_amdgcn_mfma_f32_16x16x32_bf16(
                    pf[qs][1], vf1, acc4[qs][nb], 0, 0, 0);
            }
        }
        #pragma unroll
        for (int qs = 0; qs < 2; ++qs) {
            acc5[qs] = __builtin_amdgcn_mfma_f32_16x16x32_bf16(
                pf[qs][0], ONES, acc5[qs], 0, 0, 0);
            acc5[qs] = __builtin_amdgcn_mfma_f32_16x16x32_bf16(
                pf[qs][1], ONES, acc5[qs], 0, 0, 0);
        }
        __builtin_amdgcn_s_setprio(0);

        __builtin_amdgcn_s_barrier();  // buf[cur] readers done before restage
    }

    // epilogue: normalize by acc5 (lane-local row sums), write bf16 ctx
    const int b_ = bh / HEADS;
    const int h = bh - b_ * HEADS;
    #pragma unroll
    for (int qs = 0; qs < 2; ++qs) {
        float lr[4];
        #pragma unroll
        for (int r = 0; r < 4; ++r) lr[r] = 1.0f / acc5[qs][r];
        #pragma unroll
        for (int nb = 0; nb < 4; ++nb)
            #pragma unroll
            for (int r = 0; r < 4; ++r) {
                const int s_ = q0 + wave * 32 + qs * 16 + g * 4 + r;
                ctxb[((size_t)b_ * SEQ + s_) * DIM + h * HD + nb * 16 + col] =
                    f2bf_fast(acc4[qs][nb][r] * lr[r]);
            }
    }
}

// ---------------------------------------------------------------------------
// Kernel 3: output projection, bf16 MFMA, T3-minimal 2-phase (R10 form).
// ---------------------------------------------------------------------------
__global__ __launch_bounds__(512) void out_gemm_bf16(
    const unsigned short* __restrict__ A,   // ctxb [8192][768]
    const unsigned short* __restrict__ BT,  // woT  [768][768]
    const float* __restrict__ bias, float* __restrict__ out)
{
    __shared__ __align__(16) unsigned short As[2][128][64];
    __shared__ __align__(16) unsigned short Bs[2][128][64];

    const int tid = threadIdx.x;
    const int wave = tid >> 6;
    const int lane = tid & 63;
    const int col = lane & 15;
    const int g = lane >> 4;
    const int m0 = blockIdx.y * 128;
    const int n0 = blockIdx.x * 128;
    const int wr = wave >> 2;
    const int wc = wave & 3;

    f32x4 acc[4][2] = {};

    auto STAGE = [&](int kt, int bsel) {
        #pragma unroll
        for (int it = 0; it < 2; ++it) {
            const int slot = tid + it * 512;
            const int row = slot >> 3;
            const int cg = (slot & 7) ^ (row & 7);
            gld16(A + (size_t)(m0 + row) * DIM + kt + cg * 8,
                  &As[bsel][0][0] + (size_t)slot * 8);
            gld16(BT + (size_t)(n0 + row) * DIM + kt + cg * 8,
                  &Bs[bsel][0][0] + (size_t)slot * 8);
        }
    };

    const int NKT = DIM / 64;   // 12
    STAGE(0, 0);
    asm volatile("s_waitcnt vmcnt(0)" ::: "memory");
    __builtin_amdgcn_s_barrier();

    for (int t = 0; t < NKT; ++t) {
        const int cur = t & 1;
        if (t + 1 < NKT) STAGE((t + 1) * 64, cur ^ 1);

        #pragma unroll
        for (int ks = 0; ks < 2; ++ks) {
            short8 af[4], bf[2];
            #pragma unroll
            for (int i = 0; i < 4; ++i) {
                const int ra = wr * 64 + i * 16 + col;
                af[i] = *reinterpret_cast<const short8*>(
                    &As[cur][ra][(((ks * 4 + g) ^ (ra & 7)) << 3)]);
            }
            #pragma unroll
            for (int j = 0; j < 2; ++j) {
                const int rb = wc * 32 + j * 16 + col;
                bf[j] = *reinterpret_cast<const short8*>(
                    &Bs[cur][rb][(((ks * 4 + g) ^ (rb & 7)) << 3)]);
            }
            #pragma unroll
            for (int i = 0; i < 4; ++i)
                #pragma unroll
                for (int j = 0; j < 2; ++j)
                    acc[i][j] = __builtin_amdgcn_mfma_f32_16x16x32_bf16(
                        af[i], bf[j], acc[i][j], 0, 0, 0);
        }

        if (t + 1 < NKT) {
            asm volatile("s_waitcnt vmcnt(0)" ::: "memory");
            __builtin_amdgcn_s_barrier();
        }
    }

    #pragma unroll
    for (int j = 0; j < 2; ++j) {
        const int n = n0 + wc * 32 + j * 16 + col;
        const float bj = bias[n];
        #pragma unroll
        for (int i = 0; i < 4; ++i) {
            const int m = m0 + wr * 64 + i * 16 + g * 4;
            #pragma unroll
            for (int r = 0; r < 4; ++r)
                out[(size_t)(m + r) * DIM + n] = acc[i][j][r] + bj;
        }
    }
}

// ---------------------------------------------------------------------------
// Workspace (ushort elems): qb/kb/vt/xb/ctxb 6291456 each; wqT 1769472; woT 589824
// total 33,816,576 ushorts = 67.6 MB
// ---------------------------------------------------------------------------
extern "C" void kernel_launch(void* const* d_in, const int* in_sizes, int n_in,
                              void* d_out, int out_size, void* d_ws, size_t ws_size,
                              hipStream_t stream)
{
    const float* x     = (const float*)d_in[0];
    const float* w_qkv = (const float*)d_in[1];
    const float* b_qkv = (const float*)d_in[2];
    const float* w_out = (const float*)d_in[3];
    const float* b_out = (const float*)d_in[4];
    float* out = (float*)d_out;

    const size_t QSZ = (size_t)NB * HEADS * SEQ * HD;  // 6,291,456
    unsigned short* qb   = (unsigned short*)d_ws;
    unsigned short* kb   = qb + QSZ;
    unsigned short* vt   = kb + QSZ;
    unsigned short* xb   = vt + QSZ;
    unsigned short* ctxb = xb + QSZ;
    unsigned short* wqT  = ctxb + QSZ;
    unsigned short* woT  = wqT + (size_t)NQKV * DIM;

    prep_kernel<<<3648, 256, 0, stream>>>(x, xb, w_qkv, wqT, w_out, woT);
    qkv_gemm_bf16<<<dim3(NQKV / 128, (NB * SEQ) / 128), 512, 0, stream>>>(
        xb, wqT, b_qkv, qb, kb, vt);
    attn_kernel<<<dim3((SEQ / 128) * NB * HEADS), 256, 0, stream>>>(qb, kb, vt, ctxb);
    out_gemm_bf16<<<dim3(DIM / 128, (NB * SEQ) / 128), 512, 0, stream>>>(
        ctxb, woT, b_out, out);
}

// Round 16
// 148.370 us; speedup vs baseline: 1.1841x; 1.1841x over previous
//
#include <hip/hip_runtime.h>
#include <hip/hip_bf16.h>
#include <cstdint>
#include <cstddef>

#define HEADS 12
#define HD    64
#define NB    4
#define SEQ   2048
#define DIM   768
#define NQKV  2304

// Q pre-scale: (1/sqrt(HEADS)) * log2(e)  -> scores arrive in exp2 domain
static constexpr float QSCALE = 0.2886751345948129f * 1.4426950408889634f;

typedef __attribute__((ext_vector_type(8))) short short8;
typedef __attribute__((ext_vector_type(4))) short short4v;
typedef __attribute__((ext_vector_type(4))) float f32x4;

__device__ inline unsigned short f2bf(float x) {          // RNE, for cold paths
    union { float f; uint32_t u; } v; v.f = x;
    return (unsigned short)((v.u + 0x7fffu + ((v.u >> 16) & 1u)) >> 16);
}

__device__ inline unsigned short f2bf_fast(float x) {     // compiler hw-convert
    __hip_bfloat16 h = __float2bfloat16(x);
    unsigned short u;
    __builtin_memcpy(&u, &h, 2);
    return u;
}

__device__ inline void gld16(const void* g, void* l) {
    __builtin_amdgcn_global_load_lds(
        (const __attribute__((address_space(1))) unsigned int*)g,
        (__attribute__((address_space(3))) unsigned int*)l, 16, 0, 0);
}

// ---------------------------------------------------------------------------
// Fused prep kernel: x->bf16 convert + both weight transpose-converts.
// ---------------------------------------------------------------------------
__device__ inline void transpose_tile(
    const float* __restrict__ w, unsigned short* __restrict__ wT,
    int ncols, int nrows, int bx, int by, float (*tile)[65])
{
    const int k0 = by * 64;
    const int n0 = bx * 64;
    const int tr = threadIdx.x >> 4;
    const int tc4 = (threadIdx.x & 15) * 4;
    #pragma unroll
    for (int it = 0; it < 4; ++it) {
        const int kk = tr + it * 16;
        *reinterpret_cast<float4*>(&tile[kk][tc4]) =
            *reinterpret_cast<const float4*>(w + (size_t)(k0 + kk) * ncols + n0 + tc4);
    }
    __syncthreads();
    #pragma unroll
    for (int it = 0; it < 4; ++it) {
        const int nn = tr + it * 16;
        short4v o;
        #pragma unroll
        for (int r = 0; r < 4; ++r) o[r] = (short)f2bf(tile[tc4 + r][nn]);
        *reinterpret_cast<short4v*>(wT + (size_t)(n0 + nn) * nrows + k0 + tc4) = o;
    }
}

__global__ __launch_bounds__(256) void prep_kernel(
    const float* __restrict__ x, unsigned short* __restrict__ xb,
    const float* __restrict__ wq, unsigned short* __restrict__ wqT,
    const float* __restrict__ wo, unsigned short* __restrict__ woT)
{
    __shared__ float tile[64][65];
    const int bid = blockIdx.x;
    if (bid < 3072) {
        const size_t i = ((size_t)bid * 256 + threadIdx.x) * 8;
        const float4 a = *reinterpret_cast<const float4*>(x + i);
        const float4 b = *reinterpret_cast<const float4*>(x + i + 4);
        short8 o;
        o[0] = (short)f2bf(a.x); o[1] = (short)f2bf(a.y);
        o[2] = (short)f2bf(a.z); o[3] = (short)f2bf(a.w);
        o[4] = (short)f2bf(b.x); o[5] = (short)f2bf(b.y);
        o[6] = (short)f2bf(b.z); o[7] = (short)f2bf(b.w);
        *reinterpret_cast<short8*>(xb + i) = o;
    } else if (bid < 3072 + 432) {
        const int r = bid - 3072;
        transpose_tile(wq, wqT, NQKV, DIM, r % 36, r / 36, tile);
    } else {
        const int r = bid - 3504;
        transpose_tile(wo, woT, DIM, DIM, r % 12, r / 12, tile);
    }
}

// ---------------------------------------------------------------------------
// Kernel 1: QKV GEMM, bf16 MFMA, T3-minimal 2-phase (R10 form, proven).
// ---------------------------------------------------------------------------
__global__ __launch_bounds__(512) void qkv_gemm_bf16(
    const unsigned short* __restrict__ A,   // [8192][768]
    const unsigned short* __restrict__ BT,  // [2304][768]
    const float* __restrict__ bias,
    unsigned short* __restrict__ qb, unsigned short* __restrict__ kb,
    unsigned short* __restrict__ vt)
{
    __shared__ __align__(16) unsigned short As[2][128][64];
    __shared__ __align__(16) unsigned short Bs[2][128][64];

    const int tid = threadIdx.x;
    const int wave = tid >> 6;        // 0..7
    const int lane = tid & 63;
    const int col = lane & 15;
    const int g = lane >> 4;
    const int m0 = blockIdx.y * 128;
    const int n0 = blockIdx.x * 128;
    const int wr = wave >> 2;         // 0..1  row half (64 rows)
    const int wc = wave & 3;          // 0..3  col quarter (32 cols)

    f32x4 acc[4][2] = {};

    auto STAGE = [&](int kt, int bsel) {
        #pragma unroll
        for (int it = 0; it < 2; ++it) {
            const int slot = tid + it * 512;
            const int row = slot >> 3;
            const int cg = (slot & 7) ^ (row & 7);
            gld16(A + (size_t)(m0 + row) * DIM + kt + cg * 8,
                  &As[bsel][0][0] + (size_t)slot * 8);
            gld16(BT + (size_t)(n0 + row) * DIM + kt + cg * 8,
                  &Bs[bsel][0][0] + (size_t)slot * 8);
        }
    };

    const int NKT = DIM / 64;   // 12
    STAGE(0, 0);
    asm volatile("s_waitcnt vmcnt(0)" ::: "memory");
    __builtin_amdgcn_s_barrier();

    for (int t = 0; t < NKT; ++t) {
        const int cur = t & 1;
        if (t + 1 < NKT) STAGE((t + 1) * 64, cur ^ 1);  // overlap with compute

        #pragma unroll
        for (int ks = 0; ks < 2; ++ks) {
            short8 af[4], bf[2];
            #pragma unroll
            for (int i = 0; i < 4; ++i) {
                const int ra = wr * 64 + i * 16 + col;
                af[i] = *reinterpret_cast<const short8*>(
                    &As[cur][ra][(((ks * 4 + g) ^ (ra & 7)) << 3)]);
            }
            #pragma unroll
            for (int j = 0; j < 2; ++j) {
                const int rb = wc * 32 + j * 16 + col;
                bf[j] = *reinterpret_cast<const short8*>(
                    &Bs[cur][rb][(((ks * 4 + g) ^ (rb & 7)) << 3)]);
            }
            #pragma unroll
            for (int i = 0; i < 4; ++i)
                #pragma unroll
                for (int j = 0; j < 2; ++j)
                    acc[i][j] = __builtin_amdgcn_mfma_f32_16x16x32_bf16(
                        af[i], bf[j], acc[i][j], 0, 0, 0);
        }

        if (t + 1 < NKT) {
            asm volatile("s_waitcnt vmcnt(0)" ::: "memory");  // t+1 tile landed
            __builtin_amdgcn_s_barrier();  // + all waves done reading buf[cur]
        }
    }

    // Epilogue: bias + bf16 scatter. which is block-uniform (768 % 128 == 0).
    const int which = n0 / DIM;
    #pragma unroll
    for (int j = 0; j < 2; ++j) {
        const int n = n0 + wc * 32 + j * 16 + col;
        const int rem = n - which * DIM;
        const int h = rem >> 6, dh = rem & 63;
        const float bj = bias[n];
        #pragma unroll
        for (int i = 0; i < 4; ++i) {
            const int mbase = m0 + wr * 64 + i * 16 + g * 4;
            const int b_ = mbase >> 11;
            const int s_ = mbase & 2047;
            const size_t bh = (size_t)(b_ * HEADS + h);
            if (which == 2) {
                short4v pk;
                #pragma unroll
                for (int r = 0; r < 4; ++r)
                    pk[r] = (short)f2bf(acc[i][j][r] + bj);
                *reinterpret_cast<short4v*>(vt + (bh * HD + dh) * SEQ + s_) = pk;
            } else {
                unsigned short* dst = (which == 0) ? qb : kb;
                const float sc = (which == 0) ? QSCALE : 1.0f;
                #pragma unroll
                for (int r = 0; r < 4; ++r)
                    dst[(bh * SEQ + s_ + r) * HD + dh] =
                        f2bf((acc[i][j][r] + bj) * sc);
            }
        }
    }
}

// ---------------------------------------------------------------------------
// Kernel 2: flash attention — q-register-blocked WITH 8 waves kept:
// 512 threads, each wave owns 32 q-rows (2 strips of 16) -> QBLK=256.
// K/V fragments read once per wave feed BOTH strips: LDS bytes per q-row
// ~0.55x of R13 (the measured ~68us plateau = LDS-BW floor ~57us; new
// floor ~31us). Grid 384 = 8 XCDs x 48 (6 heads/XCD, same as before).
// R13 skeleton otherwise: dbuf K/V, counted vmcnt(2), 2 barriers/tile,
// setprio, ones-MFMA row-sum. LDS 64 KB -> 2 blocks/CU (= R13's measured
// occupancy), VGPR ~88 (measured R15, same per-thread state).
// ---------------------------------------------------------------------------
__global__ __launch_bounds__(512) void attn_kernel(
    const unsigned short* __restrict__ qb, const unsigned short* __restrict__ kbuf,
    const unsigned short* __restrict__ vt, unsigned short* __restrict__ ctxb)
{
    __shared__ __align__(16) unsigned short Ks[2][64][64];    // [buf][key][hd]
    __shared__ __align__(16) unsigned short Vs[2][64][64];    // [buf][hd][key]
    __shared__ __align__(16) unsigned short Ps[8][2][16][64]; // [wave][strip][q][key]

    const int tid = threadIdx.x;
    const int wave = tid >> 6;      // 0..7
    const int lane = tid & 63;
    const int col = lane & 15;
    const int g   = lane >> 4;

    // XCD swizzle: grid = 384 blocks = 8 XCDs x 48; XCD i gets bh in [i*6,i*6+6)
    const int bid = blockIdx.x;
    const int vbid = (bid & 7) * 48 + (bid >> 3);
    const int bh = vbid >> 3;          // 0..47
    const int q0 = (vbid & 7) * 256;   // q-tile (8 tiles of 256)

    const size_t hb = (size_t)bh * SEQ * HD;

    // Q fragments for both 16-row strips (pre-scaled bf16)
    short8 qf[2][2];
    #pragma unroll
    for (int qs = 0; qs < 2; ++qs) {
        const unsigned short* src =
            qb + hb + (size_t)(q0 + wave * 32 + qs * 16 + col) * HD + g * 8;
        qf[qs][0] = *reinterpret_cast<const short8*>(src);
        qf[qs][1] = *reinterpret_cast<const short8*>(src + 32);
    }

    const short ONE = (short)0x3F80;
    const short8 ONES = {ONE, ONE, ONE, ONE, ONE, ONE, ONE, ONE};

    f32x4 acc4[2][4] = {};
    f32x4 acc5[2] = {};          // running row-sum of P per strip

    const unsigned short* Kg = kbuf + hb;
    const unsigned short* Vg = vt + hb;

    // staging: 512 threads, 1 K-chunk + 1 V-chunk each (64 rows x 8 chunks)
    const int srow = tid >> 3;       // 0..63
    const int scl  = tid & 7;
    const int scg  = scl ^ (srow & 7);

    auto STAGE = [&](int jt, int bsel) {
        const int kb0 = jt * 64;
        gld16(Kg + (size_t)(kb0 + srow) * HD + scg * 8,
              &Ks[bsel][0][0] + (size_t)tid * 8);
        gld16(Vg + (size_t)srow * SEQ + kb0 + scg * 8,
              &Vs[bsel][0][0] + (size_t)tid * 8);
    };

    const int NT = SEQ / 64;
    STAGE(0, 0);

    for (int jt = 0; jt < NT; ++jt) {
        const int cur = jt & 1;
        if (jt + 1 < NT) {
            STAGE(jt + 1, cur ^ 1);                          // prefetch next
            asm volatile("s_waitcnt vmcnt(2)" ::: "memory"); // tile jt landed
        } else {
            asm volatile("s_waitcnt vmcnt(0)" ::: "memory");
        }
        __builtin_amdgcn_s_barrier();   // all waves' tile-jt loads visible

        // S^T = K · Q^T  — K fragments shared across both q-strips
        f32x4 st[2][4] = {};
        __builtin_amdgcn_s_setprio(1);
        #pragma unroll
        for (int m = 0; m < 4; ++m) {
            const int row = m * 16 + col;
            const short8 kf0 = *reinterpret_cast<const short8*>(
                &Ks[cur][row][((g ^ (row & 7)) << 3)]);
            const short8 kf1 = *reinterpret_cast<const short8*>(
                &Ks[cur][row][(((g + 4) ^ (row & 7)) << 3)]);
            #pragma unroll
            for (int qs = 0; qs < 2; ++qs) {
                st[qs][m] = __builtin_amdgcn_mfma_f32_16x16x32_bf16(
                    kf0, qf[qs][0], st[qs][m], 0, 0, 0);
                st[qs][m] = __builtin_amdgcn_mfma_f32_16x16x32_bf16(
                    kf1, qf[qs][1], st[qs][m], 0, 0, 0);
            }
        }
        __builtin_amdgcn_s_setprio(0);

        // p = exp2(s); stage P as bf16 (wave-private LDS), both strips
        #pragma unroll
        for (int qs = 0; qs < 2; ++qs) {
            #pragma unroll
            for (int m = 0; m < 4; ++m) {
                float p[4];
                p[0] = __builtin_amdgcn_exp2f(st[qs][m][0]);
                p[1] = __builtin_amdgcn_exp2f(st[qs][m][1]);
                p[2] = __builtin_amdgcn_exp2f(st[qs][m][2]);
                p[3] = __builtin_amdgcn_exp2f(st[qs][m][3]);
                short4v pk;
                #pragma unroll
                for (int r = 0; r < 4; ++r) pk[r] = (short)f2bf_fast(p[r]);
                const int scw = (2 * m + (g >> 1)) ^ (col & 7);
                *reinterpret_cast<short4v*>(
                    &Ps[wave][qs][col][(scw << 3) + ((g & 1) << 2)]) = pk;
            }
        }

        short8 pf[2][2];
        #pragma unroll
        for (int qs = 0; qs < 2; ++qs) {
            pf[qs][0] = *reinterpret_cast<const short8*>(
                &Ps[wave][qs][col][((g ^ (col & 7)) << 3)]);
            pf[qs][1] = *reinterpret_cast<const short8*>(
                &Ps[wave][qs][col][(((g + 4) ^ (col & 7)) << 3)]);
        }

        // acc += P @ V — V fragments shared across both q-strips;
        // row-sum via ones-MFMA on the matrix pipe
        __builtin_amdgcn_s_setprio(1);
        #pragma unroll
        for (int nb = 0; nb < 4; ++nb) {
            const int row = nb * 16 + col;
            const short8 vf0 = *reinterpret_cast<const short8*>(
                &Vs[cur][row][((g ^ (row & 7)) << 3)]);
            const short8 vf1 = *reinterpret_cast<const short8*>(
                &Vs[cur][row][(((g + 4) ^ (row & 7)) << 3)]);
            #pragma unroll
            for (int qs = 0; qs < 2; ++qs) {
                acc4[qs][nb] = __builtin_amdgcn_mfma_f32_16x16x32_bf16(
                    pf[qs][0], vf0, acc4[qs][nb], 0, 0, 0);
                acc4[qs][nb] = __builtin_amdgcn_mfma_f32_16x16x32_bf16(
                    pf[qs][1], vf1, acc4[qs][nb], 0, 0, 0);
            }
        }
        #pragma unroll
        for (int qs = 0; qs < 2; ++qs) {
            acc5[qs] = __builtin_amdgcn_mfma_f32_16x16x32_bf16(
                pf[qs][0], ONES, acc5[qs], 0, 0, 0);
            acc5[qs] = __builtin_amdgcn_mfma_f32_16x16x32_bf16(
                pf[qs][1], ONES, acc5[qs], 0, 0, 0);
        }
        __builtin_amdgcn_s_setprio(0);

        __builtin_amdgcn_s_barrier();  // buf[cur] readers done before restage
    }

    // epilogue: normalize by acc5 (lane-local row sums), write bf16 ctx
    const int b_ = bh / HEADS;
    const int h = bh - b_ * HEADS;
    #pragma unroll
    for (int qs = 0; qs < 2; ++qs) {
        float lr[4];
        #pragma unroll
        for (int r = 0; r < 4; ++r) lr[r] = 1.0f / acc5[qs][r];
        #pragma unroll
        for (int nb = 0; nb < 4; ++nb)
            #pragma unroll
            for (int r = 0; r < 4; ++r) {
                const int s_ = q0 + wave * 32 + qs * 16 + g * 4 + r;
                ctxb[((size_t)b_ * SEQ + s_) * DIM + h * HD + nb * 16 + col] =
                    f2bf_fast(acc4[qs][nb][r] * lr[r]);
            }
    }
}

// ---------------------------------------------------------------------------
// Kernel 3: output projection, bf16 MFMA, T3-minimal 2-phase (R10 form).
// ---------------------------------------------------------------------------
__global__ __launch_bounds__(512) void out_gemm_bf16(
    const unsigned short* __restrict__ A,   // ctxb [8192][768]
    const unsigned short* __restrict__ BT,  // woT  [768][768]
    const float* __restrict__ bias, float* __restrict__ out)
{
    __shared__ __align__(16) unsigned short As[2][128][64];
    __shared__ __align__(16) unsigned short Bs[2][128][64];

    const int tid = threadIdx.x;
    const int wave = tid >> 6;
    const int lane = tid & 63;
    const int col = lane & 15;
    const int g = lane >> 4;
    const int m0 = blockIdx.y * 128;
    const int n0 = blockIdx.x * 128;
    const int wr = wave >> 2;
    const int wc = wave & 3;

    f32x4 acc[4][2] = {};

    auto STAGE = [&](int kt, int bsel) {
        #pragma unroll
        for (int it = 0; it < 2; ++it) {
            const int slot = tid + it * 512;
            const int row = slot >> 3;
            const int cg = (slot & 7) ^ (row & 7);
            gld16(A + (size_t)(m0 + row) * DIM + kt + cg * 8,
                  &As[bsel][0][0] + (size_t)slot * 8);
            gld16(BT + (size_t)(n0 + row) * DIM + kt + cg * 8,
                  &Bs[bsel][0][0] + (size_t)slot * 8);
        }
    };

    const int NKT = DIM / 64;   // 12
    STAGE(0, 0);
    asm volatile("s_waitcnt vmcnt(0)" ::: "memory");
    __builtin_amdgcn_s_barrier();

    for (int t = 0; t < NKT; ++t) {
        const int cur = t & 1;
        if (t + 1 < NKT) STAGE((t + 1) * 64, cur ^ 1);

        #pragma unroll
        for (int ks = 0; ks < 2; ++ks) {
            short8 af[4], bf[2];
            #pragma unroll
            for (int i = 0; i < 4; ++i) {
                const int ra = wr * 64 + i * 16 + col;
                af[i] = *reinterpret_cast<const short8*>(
                    &As[cur][ra][(((ks * 4 + g) ^ (ra & 7)) << 3)]);
            }
            #pragma unroll
            for (int j = 0; j < 2; ++j) {
                const int rb = wc * 32 + j * 16 + col;
                bf[j] = *reinterpret_cast<const short8*>(
                    &Bs[cur][rb][(((ks * 4 + g) ^ (rb & 7)) << 3)]);
            }
            #pragma unroll
            for (int i = 0; i < 4; ++i)
                #pragma unroll
                for (int j = 0; j < 2; ++j)
                    acc[i][j] = __builtin_amdgcn_mfma_f32_16x16x32_bf16(
                        af[i], bf[j], acc[i][j], 0, 0, 0);
        }

        if (t + 1 < NKT) {
            asm volatile("s_waitcnt vmcnt(0)" ::: "memory");
            __builtin_amdgcn_s_barrier();
        }
    }

    #pragma unroll
    for (int j = 0; j < 2; ++j) {
        const int n = n0 + wc * 32 + j * 16 + col;
        const float bj = bias[n];
        #pragma unroll
        for (int i = 0; i < 4; ++i) {
            const int m = m0 + wr * 64 + i * 16 + g * 4;
            #pragma unroll
            for (int r = 0; r < 4; ++r)
                out[(size_t)(m + r) * DIM + n] = acc[i][j][r] + bj;
        }
    }
}

// ---------------------------------------------------------------------------
// Workspace (ushort elems): qb/kb/vt/xb/ctxb 6291456 each; wqT 1769472; woT 589824
// total 33,816,576 ushorts = 67.6 MB
// ---------------------------------------------------------------------------
extern "C" void kernel_launch(void* const* d_in, const int* in_sizes, int n_in,
                              void* d_out, int out_size, void* d_ws, size_t ws_size,
                              hipStream_t stream)
{
    const float* x     = (const float*)d_in[0];
    const float* w_qkv = (const float*)d_in[1];
    const float* b_qkv = (const float*)d_in[2];
    const float* w_out = (const float*)d_in[3];
    const float* b_out = (const float*)d_in[4];
    float* out = (float*)d_out;

    const size_t QSZ = (size_t)NB * HEADS * SEQ * HD;  // 6,291,456
    unsigned short* qb   = (unsigned short*)d_ws;
    unsigned short* kb   = qb + QSZ;
    unsigned short* vt   = kb + QSZ;
    unsigned short* xb   = vt + QSZ;
    unsigned short* ctxb = xb + QSZ;
    unsigned short* wqT  = ctxb + QSZ;
    unsigned short* woT  = wqT + (size_t)NQKV * DIM;

    prep_kernel<<<3648, 256, 0, stream>>>(x, xb, w_qkv, wqT, w_out, woT);
    qkv_gemm_bf16<<<dim3(NQKV / 128, (NB * SEQ) / 128), 512, 0, stream>>>(
        xb, wqT, b_qkv, qb, kb, vt);
    attn_kernel<<<dim3((SEQ / 256) * NB * HEADS), 512, 0, stream>>>(qb, kb, vt, ctxb);
    out_gemm_bf16<<<dim3(DIM / 128, (NB * SEQ) / 128), 512, 0, stream>>>(
        ctxb, woT, b_out, out);
}

// Round 17
// 147.865 us; speedup vs baseline: 1.1882x; 1.0034x over previous
//
#include <hip/hip_runtime.h>
#include <hip/hip_bf16.h>
#include <cstdint>
#include <cstddef>

#define HEADS 12
#define HD    64
#define NB    4
#define SEQ   2048
#define DIM   768
#define NQKV  2304

// Q pre-scale: (1/sqrt(HEADS)) * log2(e)  -> scores arrive in exp2 domain
static constexpr float QSCALE = 0.2886751345948129f * 1.4426950408889634f;

typedef __attribute__((ext_vector_type(8))) short short8;
typedef __attribute__((ext_vector_type(4))) short short4v;
typedef __attribute__((ext_vector_type(4))) float f32x4;

__device__ inline unsigned short f2bf(float x) {          // RNE, for cold paths
    union { float f; uint32_t u; } v; v.f = x;
    return (unsigned short)((v.u + 0x7fffu + ((v.u >> 16) & 1u)) >> 16);
}

__device__ inline unsigned short f2bf_fast(float x) {     // compiler hw-convert
    __hip_bfloat16 h = __float2bfloat16(x);
    unsigned short u;
    __builtin_memcpy(&u, &h, 2);
    return u;
}

__device__ inline void gld16(const void* g, void* l) {
    __builtin_amdgcn_global_load_lds(
        (const __attribute__((address_space(1))) unsigned int*)g,
        (__attribute__((address_space(3))) unsigned int*)l, 16, 0, 0);
}

// ---------------------------------------------------------------------------
// Fused prep kernel: x->bf16 convert + both weight transpose-converts.
// ---------------------------------------------------------------------------
__device__ inline void transpose_tile(
    const float* __restrict__ w, unsigned short* __restrict__ wT,
    int ncols, int nrows, int bx, int by, float (*tile)[65])
{
    const int k0 = by * 64;
    const int n0 = bx * 64;
    const int tr = threadIdx.x >> 4;
    const int tc4 = (threadIdx.x & 15) * 4;
    #pragma unroll
    for (int it = 0; it < 4; ++it) {
        const int kk = tr + it * 16;
        *reinterpret_cast<float4*>(&tile[kk][tc4]) =
            *reinterpret_cast<const float4*>(w + (size_t)(k0 + kk) * ncols + n0 + tc4);
    }
    __syncthreads();
    #pragma unroll
    for (int it = 0; it < 4; ++it) {
        const int nn = tr + it * 16;
        short4v o;
        #pragma unroll
        for (int r = 0; r < 4; ++r) o[r] = (short)f2bf(tile[tc4 + r][nn]);
        *reinterpret_cast<short4v*>(wT + (size_t)(n0 + nn) * nrows + k0 + tc4) = o;
    }
}

__global__ __launch_bounds__(256) void prep_kernel(
    const float* __restrict__ x, unsigned short* __restrict__ xb,
    const float* __restrict__ wq, unsigned short* __restrict__ wqT,
    const float* __restrict__ wo, unsigned short* __restrict__ woT)
{
    __shared__ float tile[64][65];
    const int bid = blockIdx.x;
    if (bid < 3072) {
        const size_t i = ((size_t)bid * 256 + threadIdx.x) * 8;
        const float4 a = *reinterpret_cast<const float4*>(x + i);
        const float4 b = *reinterpret_cast<const float4*>(x + i + 4);
        short8 o;
        o[0] = (short)f2bf(a.x); o[1] = (short)f2bf(a.y);
        o[2] = (short)f2bf(a.z); o[3] = (short)f2bf(a.w);
        o[4] = (short)f2bf(b.x); o[5] = (short)f2bf(b.y);
        o[6] = (short)f2bf(b.z); o[7] = (short)f2bf(b.w);
        *reinterpret_cast<short8*>(xb + i) = o;
    } else if (bid < 3072 + 432) {
        const int r = bid - 3072;
        transpose_tile(wq, wqT, NQKV, DIM, r % 36, r / 36, tile);
    } else {
        const int r = bid - 3504;
        transpose_tile(wo, woT, DIM, DIM, r % 12, r / 12, tile);
    }
}

// ---------------------------------------------------------------------------
// Kernel 1: QKV GEMM, bf16 MFMA, T3-minimal 2-phase (R10 form, proven).
// ---------------------------------------------------------------------------
__global__ __launch_bounds__(512) void qkv_gemm_bf16(
    const unsigned short* __restrict__ A,   // [8192][768]
    const unsigned short* __restrict__ BT,  // [2304][768]
    const float* __restrict__ bias,
    unsigned short* __restrict__ qb, unsigned short* __restrict__ kb,
    unsigned short* __restrict__ vt)
{
    __shared__ __align__(16) unsigned short As[2][128][64];
    __shared__ __align__(16) unsigned short Bs[2][128][64];

    const int tid = threadIdx.x;
    const int wave = tid >> 6;        // 0..7
    const int lane = tid & 63;
    const int col = lane & 15;
    const int g = lane >> 4;
    const int m0 = blockIdx.y * 128;
    const int n0 = blockIdx.x * 128;
    const int wr = wave >> 2;         // 0..1  row half (64 rows)
    const int wc = wave & 3;          // 0..3  col quarter (32 cols)

    f32x4 acc[4][2] = {};

    auto STAGE = [&](int kt, int bsel) {
        #pragma unroll
        for (int it = 0; it < 2; ++it) {
            const int slot = tid + it * 512;
            const int row = slot >> 3;
            const int cg = (slot & 7) ^ (row & 7);
            gld16(A + (size_t)(m0 + row) * DIM + kt + cg * 8,
                  &As[bsel][0][0] + (size_t)slot * 8);
            gld16(BT + (size_t)(n0 + row) * DIM + kt + cg * 8,
                  &Bs[bsel][0][0] + (size_t)slot * 8);
        }
    };

    const int NKT = DIM / 64;   // 12
    STAGE(0, 0);
    asm volatile("s_waitcnt vmcnt(0)" ::: "memory");
    __builtin_amdgcn_s_barrier();

    for (int t = 0; t < NKT; ++t) {
        const int cur = t & 1;
        if (t + 1 < NKT) STAGE((t + 1) * 64, cur ^ 1);  // overlap with compute

        #pragma unroll
        for (int ks = 0; ks < 2; ++ks) {
            short8 af[4], bf[2];
            #pragma unroll
            for (int i = 0; i < 4; ++i) {
                const int ra = wr * 64 + i * 16 + col;
                af[i] = *reinterpret_cast<const short8*>(
                    &As[cur][ra][(((ks * 4 + g) ^ (ra & 7)) << 3)]);
            }
            #pragma unroll
            for (int j = 0; j < 2; ++j) {
                const int rb = wc * 32 + j * 16 + col;
                bf[j] = *reinterpret_cast<const short8*>(
                    &Bs[cur][rb][(((ks * 4 + g) ^ (rb & 7)) << 3)]);
            }
            #pragma unroll
            for (int i = 0; i < 4; ++i)
                #pragma unroll
                for (int j = 0; j < 2; ++j)
                    acc[i][j] = __builtin_amdgcn_mfma_f32_16x16x32_bf16(
                        af[i], bf[j], acc[i][j], 0, 0, 0);
        }

        if (t + 1 < NKT) {
            asm volatile("s_waitcnt vmcnt(0)" ::: "memory");  // t+1 tile landed
            __builtin_amdgcn_s_barrier();  // + all waves done reading buf[cur]
        }
    }

    // Epilogue: bias + bf16 scatter. which is block-uniform (768 % 128 == 0).
    const int which = n0 / DIM;
    #pragma unroll
    for (int j = 0; j < 2; ++j) {
        const int n = n0 + wc * 32 + j * 16 + col;
        const int rem = n - which * DIM;
        const int h = rem >> 6, dh = rem & 63;
        const float bj = bias[n];
        #pragma unroll
        for (int i = 0; i < 4; ++i) {
            const int mbase = m0 + wr * 64 + i * 16 + g * 4;
            const int b_ = mbase >> 11;
            const int s_ = mbase & 2047;
            const size_t bh = (size_t)(b_ * HEADS + h);
            if (which == 2) {
                short4v pk;
                #pragma unroll
                for (int r = 0; r < 4; ++r)
                    pk[r] = (short)f2bf(acc[i][j][r] + bj);
                *reinterpret_cast<short4v*>(vt + (bh * HD + dh) * SEQ + s_) = pk;
            } else {
                unsigned short* dst = (which == 0) ? qb : kb;
                const float sc = (which == 0) ? QSCALE : 1.0f;
                #pragma unroll
                for (int r = 0; r < 4; ++r)
                    dst[(bh * SEQ + s_ + r) * HD + dh] =
                        f2bf((acc[i][j][r] + bj) * sc);
            }
        }
    }
}

// ---------------------------------------------------------------------------
// Kernel 2: flash attention (R13 best: QBLK=128, 8 waves, dbuf + vmcnt(2) +
// 2 barriers, 48 KB LDS, XCD swizzle, setprio, ones-MFMA row-sum).
// ---------------------------------------------------------------------------
__global__ __launch_bounds__(512) void attn_kernel(
    const unsigned short* __restrict__ qb, const unsigned short* __restrict__ kbuf,
    const unsigned short* __restrict__ vt, unsigned short* __restrict__ ctxb)
{
    __shared__ __align__(16) unsigned short Ks[2][64][64];  // [buf][key][hd]
    __shared__ __align__(16) unsigned short Vs[2][64][64];  // [buf][hd][key]
    __shared__ __align__(16) unsigned short Ps[8][16][64];  // wave-private

    const int tid = threadIdx.x;
    const int wave = tid >> 6;
    const int lane = tid & 63;
    const int col = lane & 15;
    const int g   = lane >> 4;

    // XCD swizzle: grid = 768 blocks = 8 XCDs x 96; XCD i gets bh in [i*6,i*6+6)
    const int bid = blockIdx.x;
    const int vbid = (bid & 7) * 96 + (bid >> 3);
    const int bh = vbid >> 4;          // 0..47
    const int q0 = (vbid & 15) * 128;  // q-tile
    const int wq = q0 + wave * 16 + col;

    const size_t hb = (size_t)bh * SEQ * HD;

    short8 qf[2];
    {
        const unsigned short* src = qb + hb + (size_t)wq * HD + g * 8;
        qf[0] = *reinterpret_cast<const short8*>(src);
        qf[1] = *reinterpret_cast<const short8*>(src + 32);
    }

    // all-ones bf16 B-fragment for the row-sum MFMA
    const short ONE = (short)0x3F80;
    const short8 ONES = {ONE, ONE, ONE, ONE, ONE, ONE, ONE, ONE};

    f32x4 acc4[4] = {};
    f32x4 acc5 = {};          // running row-sum of P

    const unsigned short* Kg = kbuf + hb;
    const unsigned short* Vg = vt + hb;

    // staging: 512 threads, 1 K-chunk + 1 V-chunk each (64 rows x 8 chunks)
    const int srow = tid >> 3;       // 0..63
    const int scl  = tid & 7;
    const int scg  = scl ^ (srow & 7);

    auto STAGE = [&](int jt, int bsel) {
        const int kb0 = jt * 64;
        gld16(Kg + (size_t)(kb0 + srow) * HD + scg * 8,
              &Ks[bsel][0][0] + (size_t)tid * 8);
        gld16(Vg + (size_t)srow * SEQ + kb0 + scg * 8,
              &Vs[bsel][0][0] + (size_t)tid * 8);
    };

    const int NT = SEQ / 64;
    STAGE(0, 0);

    for (int jt = 0; jt < NT; ++jt) {
        const int cur = jt & 1;
        if (jt + 1 < NT) {
            STAGE(jt + 1, cur ^ 1);                          // prefetch next
            asm volatile("s_waitcnt vmcnt(2)" ::: "memory"); // tile jt landed
        } else {
            asm volatile("s_waitcnt vmcnt(0)" ::: "memory");
        }
        __builtin_amdgcn_s_barrier();   // all waves' tile-jt loads visible

        // S^T = K · Q^T
        f32x4 st[4] = {};
        __builtin_amdgcn_s_setprio(1);
        #pragma unroll
        for (int m = 0; m < 4; ++m) {
            const int row = m * 16 + col;
            const short8 kf0 = *reinterpret_cast<const short8*>(
                &Ks[cur][row][((g ^ (row & 7)) << 3)]);
            const short8 kf1 = *reinterpret_cast<const short8*>(
                &Ks[cur][row][(((g + 4) ^ (row & 7)) << 3)]);
            st[m] = __builtin_amdgcn_mfma_f32_16x16x32_bf16(kf0, qf[0], st[m], 0, 0, 0);
            st[m] = __builtin_amdgcn_mfma_f32_16x16x32_bf16(kf1, qf[1], st[m], 0, 0, 0);
        }
        __builtin_amdgcn_s_setprio(0);

        // p = exp2(s); stage P as bf16 (wave-private LDS); no VALU row-sum
        #pragma unroll
        for (int m = 0; m < 4; ++m) {
            float p[4];
            p[0] = __builtin_amdgcn_exp2f(st[m][0]);
            p[1] = __builtin_amdgcn_exp2f(st[m][1]);
            p[2] = __builtin_amdgcn_exp2f(st[m][2]);
            p[3] = __builtin_amdgcn_exp2f(st[m][3]);
            short4v pk;
            #pragma unroll
            for (int r = 0; r < 4; ++r) pk[r] = (short)f2bf_fast(p[r]);
            const int scw = (2 * m + (g >> 1)) ^ (col & 7);
            *reinterpret_cast<short4v*>(
                &Ps[wave][col][(scw << 3) + ((g & 1) << 2)]) = pk;
        }

        const short8 pf0 = *reinterpret_cast<const short8*>(
            &Ps[wave][col][((g ^ (col & 7)) << 3)]);
        const short8 pf1 = *reinterpret_cast<const short8*>(
            &Ps[wave][col][(((g + 4) ^ (col & 7)) << 3)]);

        // acc += P @ V ; row-sum via ones-MFMA on the same pipe
        __builtin_amdgcn_s_setprio(1);
        #pragma unroll
        for (int nb = 0; nb < 4; ++nb) {
            const int row = nb * 16 + col;
            const short8 vf0 = *reinterpret_cast<const short8*>(
                &Vs[cur][row][((g ^ (row & 7)) << 3)]);
            const short8 vf1 = *reinterpret_cast<const short8*>(
                &Vs[cur][row][(((g + 4) ^ (row & 7)) << 3)]);
            acc4[nb] = __builtin_amdgcn_mfma_f32_16x16x32_bf16(pf0, vf0, acc4[nb], 0, 0, 0);
            acc4[nb] = __builtin_amdgcn_mfma_f32_16x16x32_bf16(pf1, vf1, acc4[nb], 0, 0, 0);
        }
        acc5 = __builtin_amdgcn_mfma_f32_16x16x32_bf16(pf0, ONES, acc5, 0, 0, 0);
        acc5 = __builtin_amdgcn_mfma_f32_16x16x32_bf16(pf1, ONES, acc5, 0, 0, 0);
        __builtin_amdgcn_s_setprio(0);

        __builtin_amdgcn_s_barrier();  // buf[cur] readers done before t+1 restages it
    }

    // epilogue: normalize by acc5 (lane-local row sums), write bf16 ctx
    float lr[4];
    #pragma unroll
    for (int r = 0; r < 4; ++r) lr[r] = 1.0f / acc5[r];
    const int b_ = bh / HEADS;
    const int h = bh - b_ * HEADS;
    #pragma unroll
    for (int nb = 0; nb < 4; ++nb)
        #pragma unroll
        for (int r = 0; r < 4; ++r) {
            const int s_ = q0 + wave * 16 + g * 4 + r;
            ctxb[((size_t)b_ * SEQ + s_) * DIM + h * HD + nb * 16 + col] =
                f2bf_fast(acc4[nb][r] * lr[r]);
        }
}

// ---------------------------------------------------------------------------
// Kernel 3: output projection, bf16 MFMA, T3-minimal 2-phase (R10 form).
// ---------------------------------------------------------------------------
__global__ __launch_bounds__(512) void out_gemm_bf16(
    const unsigned short* __restrict__ A,   // ctxb [8192][768]
    const unsigned short* __restrict__ BT,  // woT  [768][768]
    const float* __restrict__ bias, float* __restrict__ out)
{
    __shared__ __align__(16) unsigned short As[2][128][64];
    __shared__ __align__(16) unsigned short Bs[2][128][64];

    const int tid = threadIdx.x;
    const int wave = tid >> 6;
    const int lane = tid & 63;
    const int col = lane & 15;
    const int g = lane >> 4;
    const int m0 = blockIdx.y * 128;
    const int n0 = blockIdx.x * 128;
    const int wr = wave >> 2;
    const int wc = wave & 3;

    f32x4 acc[4][2] = {};

    auto STAGE = [&](int kt, int bsel) {
        #pragma unroll
        for (int it = 0; it < 2; ++it) {
            const int slot = tid + it * 512;
            const int row = slot >> 3;
            const int cg = (slot & 7) ^ (row & 7);
            gld16(A + (size_t)(m0 + row) * DIM + kt + cg * 8,
                  &As[bsel][0][0] + (size_t)slot * 8);
            gld16(BT + (size_t)(n0 + row) * DIM + kt + cg * 8,
                  &Bs[bsel][0][0] + (size_t)slot * 8);
        }
    };

    const int NKT = DIM / 64;   // 12
    STAGE(0, 0);
    asm volatile("s_waitcnt vmcnt(0)" ::: "memory");
    __builtin_amdgcn_s_barrier();

    for (int t = 0; t < NKT; ++t) {
        const int cur = t & 1;
        if (t + 1 < NKT) STAGE((t + 1) * 64, cur ^ 1);

        #pragma unroll
        for (int ks = 0; ks < 2; ++ks) {
            short8 af[4], bf[2];
            #pragma unroll
            for (int i = 0; i < 4; ++i) {
                const int ra = wr * 64 + i * 16 + col;
                af[i] = *reinterpret_cast<const short8*>(
                    &As[cur][ra][(((ks * 4 + g) ^ (ra & 7)) << 3)]);
            }
            #pragma unroll
            for (int j = 0; j < 2; ++j) {
                const int rb = wc * 32 + j * 16 + col;
                bf[j] = *reinterpret_cast<const short8*>(
                    &Bs[cur][rb][(((ks * 4 + g) ^ (rb & 7)) << 3)]);
            }
            #pragma unroll
            for (int i = 0; i < 4; ++i)
                #pragma unroll
                for (int j = 0; j < 2; ++j)
                    acc[i][j] = __builtin_amdgcn_mfma_f32_16x16x32_bf16(
                        af[i], bf[j], acc[i][j], 0, 0, 0);
        }

        if (t + 1 < NKT) {
            asm volatile("s_waitcnt vmcnt(0)" ::: "memory");
            __builtin_amdgcn_s_barrier();
        }
    }

    #pragma unroll
    for (int j = 0; j < 2; ++j) {
        const int n = n0 + wc * 32 + j * 16 + col;
        const float bj = bias[n];
        #pragma unroll
        for (int i = 0; i < 4; ++i) {
            const int m = m0 + wr * 64 + i * 16 + g * 4;
            #pragma unroll
            for (int r = 0; r < 4; ++r)
                out[(size_t)(m + r) * DIM + n] = acc[i][j][r] + bj;
        }
    }
}

// ---------------------------------------------------------------------------
// Workspace (ushort elems): qb/kb/vt/xb/ctxb 6291456 each; wqT 1769472; woT 589824
// total 33,816,576 ushorts = 67.6 MB
// ---------------------------------------------------------------------------
extern "C" void kernel_launch(void* const* d_in, const int* in_sizes, int n_in,
                              void* d_out, int out_size, void* d_ws, size_t ws_size,
                              hipStream_t stream)
{
    const float* x     = (const float*)d_in[0];
    const float* w_qkv = (const float*)d_in[1];
    const float* b_qkv = (const float*)d_in[2];
    const float* w_out = (const float*)d_in[3];
    const float* b_out = (const float*)d_in[4];
    float* out = (float*)d_out;

    const size_t QSZ = (size_t)NB * HEADS * SEQ * HD;  // 6,291,456
    unsigned short* qb   = (unsigned short*)d_ws;
    unsigned short* kb   = qb + QSZ;
    unsigned short* vt   = kb + QSZ;
    unsigned short* xb   = vt + QSZ;
    unsigned short* ctxb = xb + QSZ;
    unsigned short* wqT  = ctxb + QSZ;
    unsigned short* woT  = wqT + (size_t)NQKV * DIM;

    prep_kernel<<<3648, 256, 0, stream>>>(x, xb, w_qkv, wqT, w_out, woT);
    qkv_gemm_bf16<<<dim3(NQKV / 128, (NB * SEQ) / 128), 512, 0, stream>>>(
        xb, wqT, b_qkv, qb, kb, vt);
    attn_kernel<<<dim3((SEQ / 128) * NB * HEADS), 512, 0, stream>>>(qb, kb, vt, ctxb);
    out_gemm_bf16<<<dim3(DIM / 128, (NB * SEQ) / 128), 512, 0, stream>>>(
        ctxb, woT, b_out, out);
}